// Round 12
// baseline (63.510 us; speedup 1.0000x reference)
//
#include <hip/hip_runtime.h>
#include <hip/hip_fp16.h>

#define B_ 4
#define S_ 4096
#define H_ 16
#define D_ 1024
#define HD_ 64
#define NC_ 16   // 1024 blocks; ws >= 18MB proven in R5

typedef __fp16 hf8 __attribute__((ext_vector_type(8)));
typedef _Float16 h2 __attribute__((ext_vector_type(2)));
typedef float f32x4 __attribute__((ext_vector_type(4)));

// (tanh(x)+1)/2 == sigmoid(2x)
__device__ __forceinline__ float featmap(float x) {
  float e = __expf(-2.0f * x);
  return __builtin_amdgcn_rcpf(1.0f + e);
}

// pack two f32 -> 2xf16 in a u32 (round toward zero)
__device__ __forceinline__ unsigned pk2u(float a, float b) {
  auto r = __builtin_amdgcn_cvt_pkrtz(a, b);
  unsigned u;
  __builtin_memcpy(&u, &r, 4);
  return u;
}

__device__ __forceinline__ float dot2acc(h2 a, h2 b, float c) {
#if __has_builtin(__builtin_amdgcn_fdot2)
  return __builtin_amdgcn_fdot2(a, b, c, false);
#else
  return c + (float)a[0] * (float)b[0] + (float)a[1] * (float)b[1];
#endif
}

// ---------------- Phase 1 (MFMA): kvp[c,bh] = khT(64d x 256s) @ v(256s x 64e)
// Staging v2: thread owns a 4s x 4d quad -> 8 float4 global loads per tile
// (16B/lane coalesced) + 8 ds_write_b64 at the bank floor. Swizzle
// (((d>>2)&7)<<4): write slot = (t&15)&7 (16 lanes -> 8 slots x 2 = free),
// b128 frag reads stay at the mandatory 8-phase floor.
__global__ __launch_bounds__(256, 4) void mh_p1(
    const float* __restrict__ kg, const float* __restrict__ vg,
    float* __restrict__ kvp, float* __restrict__ kredp) {
  __shared__ __align__(16) char khT[8192];   // [d=64][s=64] f16, swizzled
  __shared__ __align__(16) char vT[8192];    // [e=64][s=64] f16, swizzled
  __shared__ float ksp[256][4];              // per-thread kred partials

  const int bid = blockIdx.x;       // 0..1023
  const int bh = bid & 63, c = bid >> 6;
  const int b = bh >> 4, h = bh & 15;
  const int t = threadIdx.x, w = t >> 6, l = t & 63;

  const size_t rowbase = (size_t)b * S_ * D_ + (size_t)h * HD_;
  const float* kb = kg + rowbase;
  const float* vb = vg + rowbase;
  const int s0 = c * 256;

  f32x4 acc[4];
#pragma unroll
  for (int et = 0; et < 4; ++et) acc[et] = (f32x4){0.f, 0.f, 0.f, 0.f};
  float ksacc[4] = {0.f, 0.f, 0.f, 0.f};   // partial col-sums for d = cq+j

  const int rq = (t >> 4) * 4;             // s-quad base (0..60)
  const int cq = (t & 15) * 4;             // d-quad base (0..60)
  const int swzW = ((t & 15) & 7) << 4;    // = (((cq+j)>>2)&7)<<4, j<4
  const int wroff = (rq * 2) ^ swzW;       // byte offset within row (8B aligned)

  const int arow = l & 15;                 // frag row (d_local / e_local)
  const int kgB = (l >> 4) * 16;           // frag k-slice byte offset

#pragma unroll 1
  for (int tile = 0; tile < 4; ++tile) {
    const float* kr = kb + (size_t)(s0 + tile * 64 + rq) * D_ + cq;
    const float* vr = vb + (size_t)(s0 + tile * 64 + rq) * D_ + cq;
    float4 kv0 = *(const float4*)kr;
    float4 kv1 = *(const float4*)(kr + D_);
    float4 kv2 = *(const float4*)(kr + 2 * D_);
    float4 kv3 = *(const float4*)(kr + 3 * D_);
    float4 vv0 = *(const float4*)vr;
    float4 vv1 = *(const float4*)(vr + D_);
    float4 vv2 = *(const float4*)(vr + 2 * D_);
    float4 vv3 = *(const float4*)(vr + 3 * D_);
    const float fk[4][4] = {
        {featmap(kv0.x), featmap(kv0.y), featmap(kv0.z), featmap(kv0.w)},
        {featmap(kv1.x), featmap(kv1.y), featmap(kv1.z), featmap(kv1.w)},
        {featmap(kv2.x), featmap(kv2.y), featmap(kv2.z), featmap(kv2.w)},
        {featmap(kv3.x), featmap(kv3.y), featmap(kv3.z), featmap(kv3.w)}};
    const float fv[4][4] = {{vv0.x, vv0.y, vv0.z, vv0.w},
                            {vv1.x, vv1.y, vv1.z, vv1.w},
                            {vv2.x, vv2.y, vv2.z, vv2.w},
                            {vv3.x, vv3.y, vv3.z, vv3.w}};
#pragma unroll
    for (int j = 0; j < 4; ++j) {
      ksacc[j] += fk[0][j] + fk[1][j] + fk[2][j] + fk[3][j];
      uint2 ku = {pk2u(fk[0][j], fk[1][j]), pk2u(fk[2][j], fk[3][j])};
      uint2 vu = {pk2u(fv[0][j], fv[1][j]), pk2u(fv[2][j], fv[3][j])};
      *(uint2*)&khT[(cq + j) * 128 + wroff] = ku;
      *(uint2*)&vT [(cq + j) * 128 + wroff] = vu;
    }
    __syncthreads();
#pragma unroll
    for (int kk = 0; kk < 2; ++kk) {
      const int sbyte = kk * 64 + kgB;
      hf8 af;
      {
        const int d = w * 16 + arow;
        float4 tmp = *(const float4*)&khT[d * 128 + (sbyte ^ (((d >> 2) & 7) << 4))];
        __builtin_memcpy(&af, &tmp, 16);
      }
#pragma unroll
      for (int et = 0; et < 4; ++et) {
        const int e = et * 16 + arow;
        hf8 bf;
        float4 tmp = *(const float4*)&vT[e * 128 + (sbyte ^ (((e >> 2) & 7) << 4))];
        __builtin_memcpy(&bf, &tmp, 16);
        acc[et] = __builtin_amdgcn_mfma_f32_16x16x32_f16(af, bf, acc[et], 0, 0, 0);
      }
    }
    __syncthreads();
  }

  // ---- write kv partial: wave w owns d-rows [w*16,+16); C/D col=l&15, row=(l>>4)*4+r
  {
    float* dst = kvp + ((size_t)(c * 64 + bh)) * 4096;
    const int col = l & 15, rg4 = (l >> 4) * 4;
#pragma unroll
    for (int et = 0; et < 4; ++et)
#pragma unroll
      for (int r = 0; r < 4; ++r)
        dst[(w * 16 + rg4 + r) * 64 + et * 16 + col] = acc[et][r];
  }
  // ---- kred partials: column d gets contributions from threads t&15 == d>>2
#pragma unroll
  for (int j = 0; j < 4; ++j) ksp[t][j] = ksacc[j];
  __syncthreads();
  if (t < 64) {
    float s = 0.f;
#pragma unroll
    for (int g = 0; g < 16; ++g) s += ksp[(t >> 2) + 16 * g][t & 3];
    kredp[(size_t)(c * 64 + bh) * 64 + t] = s;
  }
}

// ---------------- Phase 1.5: reduce chunk partials -> kv, kred
__global__ __launch_bounds__(256) void mh_p15(
    const float* __restrict__ kvp, const float* __restrict__ kredp,
    float* __restrict__ kv, float* __restrict__ kred) {
  const int i = blockIdx.x * 256 + threadIdx.x;  // 0..262143
  float s = 0.f;
#pragma unroll
  for (int c = 0; c < NC_; ++c) s += kvp[(size_t)c * (64 * 4096) + i];
  kv[i] = s;
  if (i < 64 * 64) {
    float r = 0.f;
#pragma unroll
    for (int c = 0; c < NC_; ++c) r += kredp[c * 4096 + i];
    kred[i] = r + 1e-8f;
  }
}

// ---------------- Phase 2 (MFMA): out = z * qh(256x64) @ kv(64x64) per block
// Proven in R11 -- kept verbatim.
__global__ __launch_bounds__(256, 3) void mh_p2(
    const float* __restrict__ qg, const float* __restrict__ kvg,
    const float* __restrict__ kredg, float* __restrict__ outg) {
  __shared__ __align__(16) char qt[32768];   // 256 rows x 128B f16, swizzled
  __shared__ __align__(16) char kvT[8192];   // 64 e-rows x 128B f16, swizzled
  __shared__ __align__(16) char kredh[128];  // 64 f16

  const int bid = blockIdx.x;          // 0..1023
  const int bh = bid >> 4, chunk = bid & 15;
  const int b = bh >> 4, h = bh & 15;
  const int blockrow = chunk * 256;
  const int t = threadIdx.x, w = t >> 6, l = t & 63;

  // ---- stage q tile: featmap -> f16, swizzled rows (coalesced float4 reads)
  const int tr = t >> 4, tc = (t & 15) * 4;     // row base, f32 column
  const int swst = (tr & 7) << 4;               // row&7 == tr&7 (rows step by 16)
#pragma unroll
  for (int i = 0; i < 16; ++i) {
    const int row = tr + i * 16;
    float4 qv = *(const float4*)&qg[((size_t)(b * S_) + blockrow + row) * D_ + h * HD_ + tc];
    uint2 u = {pk2u(featmap(qv.x), featmap(qv.y)),
               pk2u(featmap(qv.z), featmap(qv.w))};
    *(uint2*)&qt[row * 128 + ((tc * 2) ^ swst)] = u;
  }
  // ---- stage kvT (transpose: [k][e] -> [e][k] f16, swizzled) + kred f16
#pragma unroll
  for (int i = 0; i < 16; ++i) {
    const int idx = i * 256 + t;
    const int kk = idx >> 6, e = idx & 63;
    *(__half*)&kvT[e * 128 + ((kk * 2) ^ ((e & 7) << 4))] =
        __float2half(kvg[(size_t)bh * 4096 + idx]);
  }
  if (t < 16) {
    float4 kr = *(const float4*)&kredg[bh * 64 + t * 4];
    uint2 u = {pk2u(kr.x, kr.y), pk2u(kr.z, kr.w)};
    *(uint2*)&kredh[t * 8] = u;
  }
  __syncthreads();

  const int col = l & 15;
  const int kB = (l >> 4) * 16;     // k-slice byte offset (8 f16)
  const int sw = (l & 7) << 4;

  f32x4 acc[4][4];
#pragma unroll
  for (int i = 0; i < 4; ++i)
#pragma unroll
    for (int j = 0; j < 4; ++j) acc[i][j] = (f32x4){0.f, 0.f, 0.f, 0.f};
  float zf[4];

  // kred k-slices (uniform per 16-lane group -> LDS broadcast)
  h2 kk0[4], kk1[4];
  {
    float4 r0 = *(const float4*)&kredh[kB];
    float4 r1 = *(const float4*)&kredh[64 + kB];
    __builtin_memcpy(kk0, &r0, 16);
    __builtin_memcpy(kk1, &r1, 16);
  }

#pragma unroll
  for (int rt = 0; rt < 4; ++rt) {
    const int row = w * 64 + rt * 16 + col;
    float4 a0r = *(const float4*)&qt[row * 128 + (kB ^ sw)];
    float4 a1r = *(const float4*)&qt[row * 128 + ((64 + kB) ^ sw)];
    hf8 af0, af1;
    __builtin_memcpy(&af0, &a0r, 16);
    __builtin_memcpy(&af1, &a1r, 16);
    // z partial: this lane's 16 k-elements dotted with kred
    h2 aa0[4], aa1[4];
    __builtin_memcpy(aa0, &a0r, 16);
    __builtin_memcpy(aa1, &a1r, 16);
    float zp = 0.f;
#pragma unroll
    for (int j = 0; j < 4; ++j) {
      zp = dot2acc(aa0[j], kk0[j], zp);
      zp = dot2acc(aa1[j], kk1[j], zp);
    }
    zp += __shfl_xor(zp, 16);
    zp += __shfl_xor(zp, 32);     // now every lane holds zacc for row (l&15)
    zf[rt] = __builtin_amdgcn_rcpf(zp);
#pragma unroll
    for (int et = 0; et < 4; ++et) {
      const int er = et * 16 + col;
      float4 b0r = *(const float4*)&kvT[er * 128 + (kB ^ sw)];
      float4 b1r = *(const float4*)&kvT[er * 128 + ((64 + kB) ^ sw)];
      hf8 bf0, bf1;
      __builtin_memcpy(&bf0, &b0r, 16);
      __builtin_memcpy(&bf1, &b1r, 16);
      acc[rt][et] = __builtin_amdgcn_mfma_f32_16x16x32_f16(af0, bf0, acc[rt][et], 0, 0, 0);
      acc[rt][et] = __builtin_amdgcn_mfma_f32_16x16x32_f16(af1, bf1, acc[rt][et], 0, 0, 0);
    }
  }

  // ---- epilogue: z-scale + write (C/D: col=l&15, row=(l>>4)*4+r)
  const int rg4 = (l >> 4) * 4;
#pragma unroll
  for (int rt = 0; rt < 4; ++rt) {
#pragma unroll
    for (int r = 0; r < 4; ++r) {
      const float zr = __shfl(zf[rt], rg4 + r);   // lane rg4+r holds z of that row
      const int grow = blockrow + w * 64 + rt * 16 + rg4 + r;
      float* op = &outg[((size_t)(b * S_) + grow) * D_ + h * HD_];
#pragma unroll
      for (int et = 0; et < 4; ++et)
        op[et * 16 + col] = acc[rt][et][r] * zr;
    }
  }
}

extern "C" void kernel_launch(void* const* d_in, const int* in_sizes, int n_in,
                              void* d_out, int out_size, void* d_ws, size_t ws_size,
                              hipStream_t stream) {
  const float* q = (const float*)d_in[0];
  const float* k = (const float*)d_in[1];
  const float* v = (const float*)d_in[2];
  float* out = (float*)d_out;
  float* ws = (float*)d_ws;

  float* kv    = ws;                          // 1 MiB
  float* kred  = ws + 262144;                 // 16 KiB
  float* kvp   = ws + 262144 + 4096;          // NC_ MiB
  float* kredp = kvp + (size_t)NC_ * 262144;  // NC_*16 KiB

  mh_p1 <<<64 * NC_, 256, 0, stream>>>(k, v, kvp, kredp);
  mh_p15<<<1024,     256, 0, stream>>>(kvp, kredp, kv, kred);
  mh_p2 <<<64 * 16,  256, 0, stream>>>(q, kv, kred, out);
}

// Round 13
// 63.113 us; speedup vs baseline: 1.0063x; 1.0063x over previous
//
#include <hip/hip_runtime.h>
#include <hip/hip_fp16.h>

#define B_ 4
#define S_ 4096
#define H_ 16
#define D_ 1024
#define HD_ 64
#define NC_ 16   // 1024 blocks; ws >= 18MB proven in R5

typedef __fp16 hf8 __attribute__((ext_vector_type(8)));
typedef _Float16 h2 __attribute__((ext_vector_type(2)));
typedef float f32x4 __attribute__((ext_vector_type(4)));

// (tanh(x)+1)/2 == sigmoid(2x)
__device__ __forceinline__ float featmap(float x) {
  float e = __expf(-2.0f * x);
  return __builtin_amdgcn_rcpf(1.0f + e);
}

// pack two f32 -> 2xf16 in a u32 (round toward zero)
__device__ __forceinline__ unsigned pk2u(float a, float b) {
  auto r = __builtin_amdgcn_cvt_pkrtz(a, b);
  unsigned u;
  __builtin_memcpy(&u, &r, 4);
  return u;
}

__device__ __forceinline__ float dot2acc(h2 a, h2 b, float c) {
#if __has_builtin(__builtin_amdgcn_fdot2)
  return __builtin_amdgcn_fdot2(a, b, c, false);
#else
  return c + (float)a[0] * (float)b[0] + (float)a[1] * (float)b[1];
#endif
}

// swizzle: bijective on consecutive-16 d (reads) AND stride-4 d (writes)
__device__ __forceinline__ int swzf(int d) { return ((d ^ (d >> 2)) & 15) << 4; }

// ---------------- Phase 1 (MFMA, big-tile): kvp = khT(64d x 256s) @ v(256s x 64e)
// All 256 s-rows staged at once (64KB LDS) -> ONE barrier, all 32 float4
// loads/thread in flight before it (R12 was 4 serial tiles x 2 barriers =
// latency-serialized: VALUBusy 7.6%, Occ 30%). Swizzle f(d)=(d^(d>>2))&15
// is conflict-free for b128 frag reads (consecutive d) and 2-way (free) for
// staging writes (stride-4 d) -- R12's (d>>2)&7 was 4-way on reads.
__global__ __launch_bounds__(256, 2) void mh_p1(
    const float* __restrict__ kg, const float* __restrict__ vg,
    float* __restrict__ kvp, float* __restrict__ kredp) {
  __shared__ __align__(16) char khT[32768];  // [d=64][s=256] f16, swizzled
  __shared__ __align__(16) char vT[32768];   // [e=64][s=256] f16, swizzled
  __shared__ float ksp[256][4];              // per-thread kred partials

  const int bid = blockIdx.x;       // 0..1023
  const int bh = bid & 63, c = bid >> 6;
  const int b = bh >> 4, h = bh & 15;
  const int t = threadIdx.x, w = t >> 6, l = t & 63;

  const size_t rowbase = (size_t)b * S_ * D_ + (size_t)h * HD_;
  const float* kb = kg + rowbase;
  const float* vb = vg + rowbase;
  const int s0 = c * 256;

  const int cq = (t & 15) * 4;      // d-quad base (0..60)
  const int sgrp = t >> 4;          // s-group (0..15)
  float ksacc[4] = {0.f, 0.f, 0.f, 0.f};

  // ---- stage: 4 passes x (4s x 4d quad); no barriers between passes
#pragma unroll
  for (int i = 0; i < 4; ++i) {
    const int sq = sgrp * 4 + 64 * i;           // s-quad base (0..252)
    const float* kr = kb + (size_t)(s0 + sq) * D_ + cq;
    const float* vr = vb + (size_t)(s0 + sq) * D_ + cq;
    float4 kv0 = *(const float4*)kr;
    float4 kv1 = *(const float4*)(kr + D_);
    float4 kv2 = *(const float4*)(kr + 2 * D_);
    float4 kv3 = *(const float4*)(kr + 3 * D_);
    float4 vv0 = *(const float4*)vr;
    float4 vv1 = *(const float4*)(vr + D_);
    float4 vv2 = *(const float4*)(vr + 2 * D_);
    float4 vv3 = *(const float4*)(vr + 3 * D_);
    const float fk[4][4] = {
        {featmap(kv0.x), featmap(kv0.y), featmap(kv0.z), featmap(kv0.w)},
        {featmap(kv1.x), featmap(kv1.y), featmap(kv1.z), featmap(kv1.w)},
        {featmap(kv2.x), featmap(kv2.y), featmap(kv2.z), featmap(kv2.w)},
        {featmap(kv3.x), featmap(kv3.y), featmap(kv3.z), featmap(kv3.w)}};
    const float fv[4][4] = {{vv0.x, vv0.y, vv0.z, vv0.w},
                            {vv1.x, vv1.y, vv1.z, vv1.w},
                            {vv2.x, vv2.y, vv2.z, vv2.w},
                            {vv3.x, vv3.y, vv3.z, vv3.w}};
    const int spos = sq * 2;                    // byte pos of s-quad in row
#pragma unroll
    for (int j = 0; j < 4; ++j) {
      const int d = cq + j;
      const int off = spos ^ swzf(d);
      ksacc[j] += fk[0][j] + fk[1][j] + fk[2][j] + fk[3][j];
      uint2 ku = {pk2u(fk[0][j], fk[1][j]), pk2u(fk[2][j], fk[3][j])};
      uint2 vu = {pk2u(fv[0][j], fv[1][j]), pk2u(fv[2][j], fv[3][j])};
      *(uint2*)&khT[d * 512 + off] = ku;
      *(uint2*)&vT [d * 512 + off] = vu;
    }
  }
#pragma unroll
  for (int j = 0; j < 4; ++j) ksp[t][j] = ksacc[j];
  __syncthreads();

  // ---- MFMA: wave w owns d-rows [w*16,+16) x all 64 e; K = 256 (8 steps)
  f32x4 acc[4];
#pragma unroll
  for (int et = 0; et < 4; ++et) acc[et] = (f32x4){0.f, 0.f, 0.f, 0.f};
  const int arow = l & 15;
  const int sub = (l >> 4) * 16;    // 16B sub-chunk within 64B k-window
  const int dA = w * 16 + arow;
  const int foA = swzf(dA);
  int foB[4];
#pragma unroll
  for (int et = 0; et < 4; ++et) foB[et] = swzf(et * 16 + arow);

#pragma unroll
  for (int kk = 0; kk < 8; ++kk) {
    const int sbyte = kk * 64 + sub;
    hf8 af;
    {
      float4 tmp = *(const float4*)&khT[dA * 512 + (sbyte ^ foA)];
      __builtin_memcpy(&af, &tmp, 16);
    }
#pragma unroll
    for (int et = 0; et < 4; ++et) {
      hf8 bf;
      float4 tmp = *(const float4*)&vT[(et * 16 + arow) * 512 + (sbyte ^ foB[et])];
      __builtin_memcpy(&bf, &tmp, 16);
      acc[et] = __builtin_amdgcn_mfma_f32_16x16x32_f16(af, bf, acc[et], 0, 0, 0);
    }
  }

  // ---- write kv partial: C/D col=l&15, row=(l>>4)*4+r  (verified mapping)
  {
    float* dst = kvp + ((size_t)(c * 64 + bh)) * 4096;
    const int col = l & 15, rg4 = (l >> 4) * 4;
#pragma unroll
    for (int et = 0; et < 4; ++et)
#pragma unroll
      for (int r = 0; r < 4; ++r)
        dst[(w * 16 + rg4 + r) * 64 + et * 16 + col] = acc[et][r];
  }
  // ---- kred partials: column d <- threads with t&15 == d>>2, j == d&3
  if (t < 64) {
    float s = 0.f;
#pragma unroll
    for (int g = 0; g < 16; ++g) s += ksp[(t >> 2) + 16 * g][t & 3];
    kredp[(size_t)(c * 64 + bh) * 64 + t] = s;
  }
}

// ---------------- Phase 1.5: reduce chunk partials -> kv, kred
__global__ __launch_bounds__(256) void mh_p15(
    const float* __restrict__ kvp, const float* __restrict__ kredp,
    float* __restrict__ kv, float* __restrict__ kred) {
  const int i = blockIdx.x * 256 + threadIdx.x;  // 0..262143
  float s = 0.f;
#pragma unroll
  for (int c = 0; c < NC_; ++c) s += kvp[(size_t)c * (64 * 4096) + i];
  kv[i] = s;
  if (i < 64 * 64) {
    float r = 0.f;
#pragma unroll
    for (int c = 0; c < NC_; ++c) r += kredp[c * 4096 + i];
    kred[i] = r + 1e-8f;
  }
}

// ---------------- Phase 2 (MFMA): out = z * qh(256x64) @ kv(64x64) per block
// Proven in R11/R12 -- kept verbatim.
__global__ __launch_bounds__(256, 3) void mh_p2(
    const float* __restrict__ qg, const float* __restrict__ kvg,
    const float* __restrict__ kredg, float* __restrict__ outg) {
  __shared__ __align__(16) char qt[32768];   // 256 rows x 128B f16, swizzled
  __shared__ __align__(16) char kvT[8192];   // 64 e-rows x 128B f16, swizzled
  __shared__ __align__(16) char kredh[128];  // 64 f16

  const int bid = blockIdx.x;          // 0..1023
  const int bh = bid >> 4, chunk = bid & 15;
  const int b = bh >> 4, h = bh & 15;
  const int blockrow = chunk * 256;
  const int t = threadIdx.x, w = t >> 6, l = t & 63;

  // ---- stage q tile: featmap -> f16, swizzled rows (coalesced float4 reads)
  const int tr = t >> 4, tc = (t & 15) * 4;     // row base, f32 column
  const int swst = (tr & 7) << 4;               // row&7 == tr&7 (rows step by 16)
#pragma unroll
  for (int i = 0; i < 16; ++i) {
    const int row = tr + i * 16;
    float4 qv = *(const float4*)&qg[((size_t)(b * S_) + blockrow + row) * D_ + h * HD_ + tc];
    uint2 u = {pk2u(featmap(qv.x), featmap(qv.y)),
               pk2u(featmap(qv.z), featmap(qv.w))};
    *(uint2*)&qt[row * 128 + ((tc * 2) ^ swst)] = u;
  }
  // ---- stage kvT (transpose: [k][e] -> [e][k] f16, swizzled) + kred f16
#pragma unroll
  for (int i = 0; i < 16; ++i) {
    const int idx = i * 256 + t;
    const int kk = idx >> 6, e = idx & 63;
    *(__half*)&kvT[e * 128 + ((kk * 2) ^ ((e & 7) << 4))] =
        __float2half(kvg[(size_t)bh * 4096 + idx]);
  }
  if (t < 16) {
    float4 kr = *(const float4*)&kredg[bh * 64 + t * 4];
    uint2 u = {pk2u(kr.x, kr.y), pk2u(kr.z, kr.w)};
    *(uint2*)&kredh[t * 8] = u;
  }
  __syncthreads();

  const int col = l & 15;
  const int kB = (l >> 4) * 16;     // k-slice byte offset (8 f16)
  const int sw = (l & 7) << 4;

  f32x4 acc[4][4];
#pragma unroll
  for (int i = 0; i < 4; ++i)
#pragma unroll
    for (int j = 0; j < 4; ++j) acc[i][j] = (f32x4){0.f, 0.f, 0.f, 0.f};
  float zf[4];

  // kred k-slices (uniform per 16-lane group -> LDS broadcast)
  h2 kk0[4], kk1[4];
  {
    float4 r0 = *(const float4*)&kredh[kB];
    float4 r1 = *(const float4*)&kredh[64 + kB];
    __builtin_memcpy(kk0, &r0, 16);
    __builtin_memcpy(kk1, &r1, 16);
  }

#pragma unroll
  for (int rt = 0; rt < 4; ++rt) {
    const int row = w * 64 + rt * 16 + col;
    float4 a0r = *(const float4*)&qt[row * 128 + (kB ^ sw)];
    float4 a1r = *(const float4*)&qt[row * 128 + ((64 + kB) ^ sw)];
    hf8 af0, af1;
    __builtin_memcpy(&af0, &a0r, 16);
    __builtin_memcpy(&af1, &a1r, 16);
    // z partial: this lane's 16 k-elements dotted with kred
    h2 aa0[4], aa1[4];
    __builtin_memcpy(aa0, &a0r, 16);
    __builtin_memcpy(aa1, &a1r, 16);
    float zp = 0.f;
#pragma unroll
    for (int j = 0; j < 4; ++j) {
      zp = dot2acc(aa0[j], kk0[j], zp);
      zp = dot2acc(aa1[j], kk1[j], zp);
    }
    zp += __shfl_xor(zp, 16);
    zp += __shfl_xor(zp, 32);     // now every lane holds zacc for row (l&15)
    zf[rt] = __builtin_amdgcn_rcpf(zp);
#pragma unroll
    for (int et = 0; et < 4; ++et) {
      const int er = et * 16 + col;
      float4 b0r = *(const float4*)&kvT[er * 128 + (kB ^ sw)];
      float4 b1r = *(const float4*)&kvT[er * 128 + ((64 + kB) ^ sw)];
      hf8 bf0, bf1;
      __builtin_memcpy(&bf0, &b0r, 16);
      __builtin_memcpy(&bf1, &b1r, 16);
      acc[rt][et] = __builtin_amdgcn_mfma_f32_16x16x32_f16(af0, bf0, acc[rt][et], 0, 0, 0);
      acc[rt][et] = __builtin_amdgcn_mfma_f32_16x16x32_f16(af1, bf1, acc[rt][et], 0, 0, 0);
    }
  }

  // ---- epilogue: z-scale + write (C/D: col=l&15, row=(l>>4)*4+r)
  const int rg4 = (l >> 4) * 4;
#pragma unroll
  for (int rt = 0; rt < 4; ++rt) {
#pragma unroll
    for (int r = 0; r < 4; ++r) {
      const float zr = __shfl(zf[rt], rg4 + r);   // lane rg4+r holds z of that row
      const int grow = blockrow + w * 64 + rt * 16 + rg4 + r;
      float* op = &outg[((size_t)(b * S_) + grow) * D_ + h * HD_];
#pragma unroll
      for (int et = 0; et < 4; ++et)
        op[et * 16 + col] = acc[rt][et][r] * zr;
    }
  }
}

extern "C" void kernel_launch(void* const* d_in, const int* in_sizes, int n_in,
                              void* d_out, int out_size, void* d_ws, size_t ws_size,
                              hipStream_t stream) {
  const float* q = (const float*)d_in[0];
  const float* k = (const float*)d_in[1];
  const float* v = (const float*)d_in[2];
  float* out = (float*)d_out;
  float* ws = (float*)d_ws;

  float* kv    = ws;                          // 1 MiB
  float* kred  = ws + 262144;                 // 16 KiB
  float* kvp   = ws + 262144 + 4096;          // NC_ MiB
  float* kredp = kvp + (size_t)NC_ * 262144;  // NC_*16 KiB

  mh_p1 <<<64 * NC_, 256, 0, stream>>>(k, v, kvp, kredp);
  mh_p15<<<1024,     256, 0, stream>>>(kvp, kredp, kv, kred);
  mh_p2 <<<64 * 16,  256, 0, stream>>>(q, kv, kred, out);
}